// Round 1
// baseline (467.996 us; speedup 1.0000x reference)
//
#include <hip/hip_runtime.h>
#include <hip/hip_bf16.h>
#include <stdint.h>

#define N_TOT    131072
#define DIM      256
#define KCODES   1024
#define BM       128          // rows per block (4 waves x 32 rows)
#define BN       64           // codewords per LDS chunk
#define RSTRIDE  264          // ushorts per embB row: 528 B = 33*16B, breaks 512B bank pattern
#define NCHUNK   (KCODES / BN)
#define THW      16384        // 16*32*32
#define OUT_ELEMS 33554432ULL // 8*256*16*32*32

typedef short short8 __attribute__((ext_vector_type(8)));
typedef float f32x4  __attribute__((ext_vector_type(4)));

__device__ __forceinline__ unsigned short f2bf_rne(float f) {
  union { float f; unsigned int u; } c; c.f = f;
  unsigned int u = c.u;
  unsigned int r = u + 0x7FFFu + ((u >> 16) & 1u);
  return (unsigned short)(r >> 16);
}

__device__ __forceinline__ void async_cp16(void* lds, const void* gsrc) {
  __builtin_amdgcn_global_load_lds(
      (const __attribute__((address_space(1))) void*)gsrc,
      (__attribute__((address_space(3))) void*)lds, 16, 0, 0);
}

// ---------------- prep: embB(bf16, padded rows), e2, embT, zero loss ----------------
__global__ __launch_bounds__(64) void k_prep(const float* __restrict__ emb,
                                             unsigned short* __restrict__ embB,
                                             float* __restrict__ e2,
                                             float* __restrict__ embT,
                                             float* __restrict__ lossAcc) {
  const int k = blockIdx.x;
  const int t = threadIdx.x;
  const float4 v = ((const float4*)(emb + (size_t)k * DIM))[t];   // c = 4t..4t+3
  float s = v.x * v.x + v.y * v.y + v.z * v.z + v.w * v.w;
  ushort4 bv;
  bv.x = f2bf_rne(v.x); bv.y = f2bf_rne(v.y);
  bv.z = f2bf_rne(v.z); bv.w = f2bf_rne(v.w);
  ((ushort4*)(embB + (size_t)k * RSTRIDE))[t] = bv;
  const int c = 4 * t;
  embT[(size_t)(c + 0) * KCODES + k] = v.x;
  embT[(size_t)(c + 1) * KCODES + k] = v.y;
  embT[(size_t)(c + 2) * KCODES + k] = v.z;
  embT[(size_t)(c + 3) * KCODES + k] = v.w;
  #pragma unroll
  for (int m = 32; m; m >>= 1) s += __shfl_xor(s, m, 64);
  if (t == 0) e2[k] = s;
  if (k == 0 && t == 0) *lossAcc = 0.0f;
}

// ---------------- main: fused distance-GEMM + argmin + loss partials ----------------
__global__ __launch_bounds__(256) void k_gemm_argmin(
    const float* __restrict__ x, const unsigned short* __restrict__ embB,
    const float* __restrict__ e2, int* __restrict__ idxOut,
    float* __restrict__ lossAcc) {
  __shared__ __align__(16) unsigned short eT[BN * RSTRIDE];   // 33792 B

  const int tid  = threadIdx.x;
  const int wave = tid >> 6;
  const int lane = tid & 63;
  const int q    = lane >> 4;     // quad 0..3
  const int l15  = lane & 15;
  const int nw0  = blockIdx.x * BM + wave * 32;   // wave's first row
  const int b    = nw0 >> 14;                      // batch index (block-uniform; 16384 % 128 == 0)

  // ---- load A fragments (x rows, scaled by -2, bf16) into registers; accumulate ||x||^2 ----
  // A-operand layout: lane holds A[m = l15][k = q*8 + j], j=0..7, per 32-wide k-step.
  short8 A[2][8];
  float x2sum = 0.0f;
  #pragma unroll
  for (int mf = 0; mf < 2; ++mf) {
    const int n   = nw0 + mf * 16 + l15;
    const int thw = n & (THW - 1);
    const float* __restrict__ xr = x + (size_t)b * DIM * THW + thw;
    #pragma unroll
    for (int ks = 0; ks < 8; ++ks) {
      const int c0 = ks * 32 + q * 8;
      short8 a;
      #pragma unroll
      for (int j = 0; j < 8; ++j) {
        float v = xr[(size_t)(c0 + j) * THW];
        x2sum += v * v;
        a[j] = (short)f2bf_rne(-2.0f * v);
      }
      A[mf][ks] = a;
    }
  }

  float mins[2][4];
  int   mini[2][4];
  #pragma unroll
  for (int mf = 0; mf < 2; ++mf)
    #pragma unroll
    for (int r = 0; r < 4; ++r) { mins[mf][r] = 3.4e38f; mini[mf][r] = 0; }

  // ---- stream codebook chunks through LDS; MFMA; running argmin ----
  for (int ch = 0; ch < NCHUNK; ++ch) {
    const int cb = ch * BN;
    const char* gsrc = (const char*)(embB + (size_t)cb * RSTRIDE);
    for (int i = tid; i < (BN * RSTRIDE * 2) / 16; i += 256)     // 2112 x 16B
      async_cp16(((char*)eT) + i * 16, gsrc + i * 16);
    __syncthreads();

    #pragma unroll
    for (int nf = 0; nf < 4; ++nf) {
      f32x4 acc0 = {0.f, 0.f, 0.f, 0.f};
      f32x4 acc1 = {0.f, 0.f, 0.f, 0.f};
      // B-operand: lane holds B[k = q*8 + j][n = l15] = E[cod = l15][c = q*8 + j]
      const unsigned short* br = eT + (nf * 16 + l15) * RSTRIDE + q * 8;
      #pragma unroll
      for (int ks = 0; ks < 8; ++ks) {
        short8 bf = *(const short8*)(br + ks * 32);
        acc0 = __builtin_amdgcn_mfma_f32_16x16x32_bf16(A[0][ks], bf, acc0, 0, 0, 0);
        acc1 = __builtin_amdgcn_mfma_f32_16x16x32_bf16(A[1][ks], bf, acc1, 0, 0, 0);
      }
      // D layout: row = q*4 + r (within 16-row frag), col = l15 (codeword)
      const int   cod = cb + nf * 16 + l15;
      const float e2v = e2[cod];
      #pragma unroll
      for (int r = 0; r < 4; ++r) {
        float s0 = acc0[r] + e2v;
        if (s0 < mins[0][r]) { mins[0][r] = s0; mini[0][r] = cod; }
        float s1 = acc1[r] + e2v;
        if (s1 < mins[1][r]) { mins[1][r] = s1; mini[1][r] = cod; }
      }
    }
    __syncthreads();
  }

  // ---- reduce argmin across the 16 lanes holding the same rows (cols of the frag) ----
  #pragma unroll
  for (int m = 1; m <= 8; m <<= 1) {
    #pragma unroll
    for (int mf = 0; mf < 2; ++mf)
      #pragma unroll
      for (int r = 0; r < 4; ++r) {
        float os = __shfl_xor(mins[mf][r], m, 64);
        int   oi = __shfl_xor(mini[mf][r], m, 64);
        if (os < mins[mf][r] || (os == mins[mf][r] && oi < mini[mf][r])) {
          mins[mf][r] = os; mini[mf][r] = oi;
        }
      }
  }

  float sstar = 0.0f;
  if (l15 == 0) {
    #pragma unroll
    for (int mf = 0; mf < 2; ++mf)
      #pragma unroll
      for (int r = 0; r < 4; ++r) {
        idxOut[nw0 + mf * 16 + q * 4 + r] = mini[mf][r];
        sstar += mins[mf][r];
      }
  }
  // loss partial: sum over wave of ||x||^2 (all lanes) + s* (quad leaders)
  float tot = x2sum + sstar;
  #pragma unroll
  for (int m = 32; m; m >>= 1) tot += __shfl_xor(tot, m, 64);
  if (lane == 0) atomicAdd(lossAcc, tot);
}

// ---------------- epilogue: gather codewords channel-major + finalize loss ----------------
#define ONB 512   // n rows per block
__global__ __launch_bounds__(256) void k_out(
    const float* __restrict__ embT, const int* __restrict__ idx,
    float* __restrict__ out, const float* __restrict__ lossAcc) {
  __shared__ __align__(16) float rowbuf[2][KCODES];   // 8 KB double buffer
  __shared__ int ids[ONB];                            // 2 KB
  const int tid = threadIdx.x;
  const int n0  = blockIdx.x * ONB;

  if (blockIdx.x == 0 && tid == 0)
    out[OUT_ELEMS] = 1.25f * lossAcc[0] * (1.0f / (float)OUT_ELEMS);

  for (int i = tid; i < ONB; i += 256) ids[i] = idx[n0 + i];
  const int b    = n0 >> 14;
  const int thw0 = n0 & (THW - 1);
  float* __restrict__ ob = out + (size_t)b * DIM * THW + thw0;

  async_cp16(&rowbuf[0][tid * 4], embT + tid * 4);    // stage c = 0 (4 KB: 256 thr x 16 B)
  for (int c = 0; c < DIM; ++c) {
    __syncthreads();  // staging of row c complete (vmcnt drained); ids visible on first iter
    if (c + 1 < DIM)
      async_cp16(&rowbuf[(c + 1) & 1][tid * 4],
                 embT + (size_t)(c + 1) * KCODES + tid * 4);
    const float* rb = rowbuf[c & 1];
    float* oc = ob + (size_t)c * THW;
    #pragma unroll
    for (int r = 0; r < ONB / 256; ++r) {
      int i = tid + r * 256;
      oc[i] = rb[ids[i]];      // LDS gather; coalesced 4B store
    }
  }
}

extern "C" void kernel_launch(void* const* d_in, const int* in_sizes, int n_in,
                              void* d_out, int out_size, void* d_ws, size_t ws_size,
                              hipStream_t stream) {
  const float* x   = (const float*)d_in[0];
  const float* emb = (const float*)d_in[1];
  float* out = (float*)d_out;
  char* ws = (char*)d_ws;

  // workspace layout (all 16B aligned), total ~2.02 MB
  unsigned short* embB = (unsigned short*)(ws);          // 1024*264*2 = 540672 B
  float* e2      = (float*)(ws + 540672);                // 4096 B
  float* embT    = (float*)(ws + 544768);                // 256*1024*4 = 1048576 B
  int*   idx     = (int*)(ws + 1593344);                 // 131072*4 = 524288 B
  float* lossAcc = (float*)(ws + 2117632);               // 4 B

  k_prep<<<KCODES, 64, 0, stream>>>(emb, embB, e2, embT, lossAcc);
  k_gemm_argmin<<<N_TOT / BM, 256, 0, stream>>>(x, embB, e2, idx, lossAcc);
  k_out<<<N_TOT / ONB, 256, 0, stream>>>(embT, idx, out, lossAcc);
}